// Round 1
// baseline (2112.594 us; speedup 1.0000x reference)
//
#include <hip/hip_runtime.h>
#include <math.h>

#define HW 4096

// ---------------- Stage 1a: spatial complex LayerNorm ----------------
// in : x_real/x_imag (B,T,D,H,W); out: xc layout-A (BT,HW,128)
__global__ __launch_bounds__(256) void k_ln_s(
    const float* __restrict__ xr, const float* __restrict__ xi,
    const float* __restrict__ lw, const float* __restrict__ lb,
    float* __restrict__ out)
{
    __shared__ float tile[64*129];
    __shared__ float ps[64*4];
    __shared__ float ps2[64*4];
    __shared__ float mu_s[64];
    __shared__ float rs_s[64];
    int bt  = blockIdx.x;
    int hw0 = blockIdx.y * 64;
    int tid = threadIdx.x;
    int wl = tid & 63;
    int q  = tid >> 6;
    float s = 0.f, s2 = 0.f;
    for (int c = q; c < 128; c += 4) {
        const float* src = (c < 64) ? xr : xi;
        int d = c & 63;
        float v = src[(bt*64 + d)*HW + hw0 + wl];   // coalesced across wl
        tile[wl*129 + c] = v;
        s += v; s2 += v*v;
    }
    ps[wl*4 + q] = s;
    ps2[wl*4 + q] = s2;
    __syncthreads();
    if (tid < 64) {
        float ss = ps[tid*4+0]+ps[tid*4+1]+ps[tid*4+2]+ps[tid*4+3];
        float qq = ps2[tid*4+0]+ps2[tid*4+1]+ps2[tid*4+2]+ps2[tid*4+3];
        float mu = ss * 0.0078125f;
        float var = qq * 0.0078125f - mu*mu;
        mu_s[tid] = mu;
        rs_s[tid] = rsqrtf(var + 1e-5f);
    }
    __syncthreads();
    int c = tid & 127;
    int r = tid >> 7;
    float wc = lw[c], bc = lb[c];
    for (int wi = r; wi < 64; wi += 2) {
        float v = tile[wi*129 + c];
        out[(bt*HW + hw0 + wi)*128 + c] = (v - mu_s[wi]) * rs_s[wi] * wc + bc;
    }
}

// ---------------- Stage 1b: 3x3 conv (SAME) + bias + residual ----------------
// block = (bt, h), 128 threads = out channel; acc[64] = one W row per thread.
__global__ __launch_bounds__(128) void k_conv(
    const float* __restrict__ xc, const float* __restrict__ cw,
    const float* __restrict__ cb,
    const float* __restrict__ xr, const float* __restrict__ xi,
    float* __restrict__ x1)
{
    __shared__ float lds[64*129];   // reused: staging tile then transpose tile
    int bt = blockIdx.x;
    int h  = blockIdx.y;
    int o  = threadIdx.x;
    float acc[64];
    float bias = cb[o];
    #pragma unroll
    for (int w = 0; w < 64; w++) acc[w] = bias;

    for (int ci = 0; ci < 8; ci++) {          // 8 chunks of 16 in-channels
        __syncthreads();
        // stage tile[3 rows][66 cols (w=-1..64)][16 ch], zero-padded
        for (int l = o; l < 3168; l += 128) {
            int j = l & 15;
            int colr = l >> 4;
            int col = colr % 66;
            int r = colr / 66;
            int gh = h + r - 1;
            float v = 0.f;
            if ((unsigned)gh < 64u && col >= 1 && col <= 64)
                v = xc[(bt*HW + gh*64 + (col-1))*128 + ci*16 + j];
            lds[l] = v;
        }
        __syncthreads();
        const float4* t4 = (const float4*)lds;
        for (int kh = 0; kh < 3; kh++) {
            for (int i4 = 0; i4 < 4; i4++) {
                int icg = ci*16 + i4*4;
                float4 k0, k1, k2;
                k0.x = cw[((kh*3+0)*128 + icg+0)*128 + o];
                k0.y = cw[((kh*3+0)*128 + icg+1)*128 + o];
                k0.z = cw[((kh*3+0)*128 + icg+2)*128 + o];
                k0.w = cw[((kh*3+0)*128 + icg+3)*128 + o];
                k1.x = cw[((kh*3+1)*128 + icg+0)*128 + o];
                k1.y = cw[((kh*3+1)*128 + icg+1)*128 + o];
                k1.z = cw[((kh*3+1)*128 + icg+2)*128 + o];
                k1.w = cw[((kh*3+1)*128 + icg+3)*128 + o];
                k2.x = cw[((kh*3+2)*128 + icg+0)*128 + o];
                k2.y = cw[((kh*3+2)*128 + icg+1)*128 + o];
                k2.z = cw[((kh*3+2)*128 + icg+2)*128 + o];
                k2.w = cw[((kh*3+2)*128 + icg+3)*128 + o];
                // sliding 3-col window of float4 channel chunks (LDS broadcast)
                float4 c0 = t4[(kh*66 + 0)*4 + i4];
                float4 c1 = t4[(kh*66 + 1)*4 + i4];
                #pragma unroll
                for (int w = 0; w < 64; w++) {
                    float4 c2 = t4[(kh*66 + w + 2)*4 + i4];
                    acc[w] += c0.x*k0.x + c0.y*k0.y + c0.z*k0.z + c0.w*k0.w
                            + c1.x*k1.x + c1.y*k1.y + c1.z*k1.z + c1.w*k1.w
                            + c2.x*k2.x + c2.y*k2.y + c2.z*k2.z + c2.w*k2.w;
                    c0 = c1; c1 = c2;
                }
            }
        }
    }
    // residual add (original x, native layout; per-thread contiguous row)
    {
        int d = o & 63;
        const float* rsp = (o < 64) ? xr : xi;
        const float4* rb4 = (const float4*)&rsp[(bt*64 + d)*HW + h*64];
        #pragma unroll
        for (int w4 = 0; w4 < 16; w4++) {
            float4 v = rb4[w4];
            acc[w4*4+0] += v.x;
            acc[w4*4+1] += v.y;
            acc[w4*4+2] += v.z;
            acc[w4*4+3] += v.w;
        }
    }
    __syncthreads();
    #pragma unroll
    for (int w = 0; w < 64; w++) lds[w*129 + o] = acc[w];
    __syncthreads();
    int tok0 = bt*HW + h*64;
    for (int l = o; l < 8192; l += 128) {
        int w = l >> 7;
        int c = l & 127;
        x1[(tok0 + w)*128 + c] = lds[w*129 + c];   // coalesced layout-A write
    }
}

// ---------------- Stage 2: temporal LN + encode + scan + decode + residual ----------------
// one 64-thread wave per n=(b,h,w); thread = mode index
__global__ __launch_bounds__(64) void k_temporal(
    const float* __restrict__ x1, float* __restrict__ x2,
    const float* __restrict__ lw, const float* __restrict__ lb,
    const float* __restrict__ dt,
    const float* __restrict__ lamr, const float* __restrict__ lami,
    const float* __restrict__ sbr, const float* __restrict__ sbi,
    const float* __restrict__ encr, const float* __restrict__ enci,
    const float* __restrict__ decr, const float* __restrict__ deci,
    const float* __restrict__ nzr, const float* __restrict__ nzi)
{
    __shared__ float zA[2048];   // original x1 rows (16 x 128)
    __shared__ float zB[2048];   // normalized, then reused for h
    int n = blockIdx.x;
    int b = n >> 12;
    int hw = n & 4095;
    int e = threadIdx.x;
    float lwr = lw[e], lwi = lw[e+64], lbr = lb[e], lbi = lb[e+64];
    for (int t = 0; t < 16; t++) {
        const float* src = &x1[(size_t)((b*16 + t)*HW + hw)*128];
        float v0 = src[e];
        float v1 = src[e+64];
        zA[t*128 + e] = v0;
        zA[t*128 + 64 + e] = v1;
        float s = v0 + v1;
        float s2 = v0*v0 + v1*v1;
        #pragma unroll
        for (int off = 32; off > 0; off >>= 1) {
            s  += __shfl_down(s, off, 64);
            s2 += __shfl_down(s2, off, 64);
        }
        float mu  = __shfl(s, 0, 64) * 0.0078125f;
        float var = __shfl(s2, 0, 64) * 0.0078125f - mu*mu;
        float rsq = rsqrtf(var + 1e-5f);
        zB[t*128 + e]      = (v0 - mu)*rsq*lwr + lbr;
        zB[t*128 + 64 + e] = (v1 - mu)*rsq*lwi + lbi;
    }
    __syncthreads();
    // encode: u_pre[t][e] = sum_d z[t][d] * Eb[d][e]   (complex)
    float sr[16], si[16];
    #pragma unroll
    for (int t = 0; t < 16; t++) { sr[t] = 0.f; si[t] = 0.f; }
    const float4* zB4 = (const float4*)zB;
    for (int d4 = 0; d4 < 16; d4++) {
        int d = d4*4;
        float er0 = encr[(d+0)*64 + e], ei0 = enci[(d+0)*64 + e];
        float er1 = encr[(d+1)*64 + e], ei1 = enci[(d+1)*64 + e];
        float er2 = encr[(d+2)*64 + e], ei2 = enci[(d+2)*64 + e];
        float er3 = encr[(d+3)*64 + e], ei3 = enci[(d+3)*64 + e];
        #pragma unroll
        for (int t = 0; t < 16; t++) {
            float4 xr4 = zB4[t*32 + d4];
            float4 xi4 = zB4[t*32 + 16 + d4];
            sr[t] += xr4.x*er0 - xi4.x*ei0 + xr4.y*er1 - xi4.y*ei1
                   + xr4.z*er2 - xi4.z*ei2 + xr4.w*er3 - xi4.w*ei3;
            si[t] += xr4.x*ei0 + xi4.x*er0 + xr4.y*ei1 + xi4.y*er1
                   + xr4.z*ei2 + xi4.z*er2 + xr4.w*ei3 + xi4.w*er3;
        }
    }
    // per-mode params + forcing + noise + sequential scan (T=16)
    float lr = lamr[e];
    float sp = (lr > 20.f) ? lr : log1pf(expf(lr));
    float lre = -sp;
    float lim = lami[e];
    float inv = 1.f / (lre*lre + lim*lim);
    float br = sbr[e], bi = sbi[e];
    float hrp = 0.f, hip = 0.f;
    float hsr[16], hsi[16];
    #pragma unroll
    for (int t = 0; t < 16; t++) {
        float dtv = dt[b*16 + t];
        float ex = expf(lre*dtv);
        float sn, cs;
        sincosf(lim*dtv, &sn, &cs);
        float ar = ex*cs, ai = ex*sn;                 // a = exp(lam*dt)
        float numr = ar - 1.f, numi = ai;             // forcing = (a-1)/lam
        float fr = (numr*lre + numi*lim)*inv;
        float fi = (numi*lre - numr*lim)*inv;
        float tr = sr[t] + br, ti = si[t] + bi;
        float ur = tr*fr - ti*fi;
        float ui = tr*fi + ti*fr;
        float nsc = 0.01f * sqrtf(dtv);
        ur += nsc * nzr[(n*16 + t)*64 + e];
        ui += nsc * nzi[(n*16 + t)*64 + e];
        float nh_r = ar*hrp - ai*hip + ur;
        float nh_i = ar*hip + ai*hrp + ui;
        hrp = nh_r; hip = nh_i;
        hsr[t] = hrp; hsi[t] = hip;
    }
    __syncthreads();
    #pragma unroll
    for (int t = 0; t < 16; t++) {
        zB[t*128 + e]      = hsr[t];
        zB[t*128 + 64 + e] = hsi[t];
    }
    __syncthreads();
    // decode: drift[t][d] = Re( sum_e h[t][e] * Db[e][d] ), d = thread
    float drf[16];
    #pragma unroll
    for (int t = 0; t < 16; t++) drf[t] = 0.f;
    for (int e4 = 0; e4 < 16; e4++) {
        int ee = e4*4;
        float d0 = decr[(ee+0)*64 + e], i0 = deci[(ee+0)*64 + e];
        float d1 = decr[(ee+1)*64 + e], i1 = deci[(ee+1)*64 + e];
        float d2 = decr[(ee+2)*64 + e], i2 = deci[(ee+2)*64 + e];
        float d3 = decr[(ee+3)*64 + e], i3 = deci[(ee+3)*64 + e];
        #pragma unroll
        for (int t = 0; t < 16; t++) {
            float4 hr4 = zB4[t*32 + e4];
            float4 hi4 = zB4[t*32 + 16 + e4];
            drf[t] += hr4.x*d0 - hi4.x*i0 + hr4.y*d1 - hi4.y*i1
                    + hr4.z*d2 - hi4.z*i2 + hr4.w*d3 - hi4.w*i3;
        }
    }
    #pragma unroll
    for (int t = 0; t < 16; t++) {
        float* dst = &x2[(size_t)((b*16 + t)*HW + hw)*128];
        dst[e]      = drf[t] + zA[t*128 + e];   // drift is real-only
        dst[e + 64] = zA[t*128 + 64 + e];
    }
}

// ---------------- Stage 3: dense MoE FFN + residual ----------------
// 32 tokens / block, 256 threads = 2 token-groups x 128 units
__global__ __launch_bounds__(256) void k_moe(
    const float* __restrict__ x2, float* __restrict__ xo,
    const float* __restrict__ rw, const float* __restrict__ rb,
    const float* __restrict__ w1, const float* __restrict__ b1,
    const float* __restrict__ w2, const float* __restrict__ b2)
{
    __shared__ float ltok[32*132];   // pad 132 -> float4-aligned rows
    __shared__ float hdn[32*132];
    __shared__ float gates[32*4];
    int tok0 = blockIdx.x * 32;
    int tid = threadIdx.x;
    for (int l = tid; l < 4096; l += 256)
        ltok[(l >> 7)*132 + (l & 127)] = x2[(size_t)tok0*128 + l];
    __syncthreads();
    if (tid < 128) {
        int token = tid >> 2, e = tid & 3;
        float acc = rb[e];
        for (int c = 0; c < 128; c++)
            acc += ltok[token*132 + c] * rw[c*4 + e];
        gates[token*4 + e] = acc;
    }
    __syncthreads();
    if (tid < 32) {
        float g0 = gates[tid*4+0], g1 = gates[tid*4+1];
        float g2 = gates[tid*4+2], g3 = gates[tid*4+3];
        float m = fmaxf(fmaxf(g0,g1), fmaxf(g2,g3));
        float e0 = expf(g0-m), e1 = expf(g1-m), e2 = expf(g2-m), e3 = expf(g3-m);
        float iv = 1.f/(e0+e1+e2+e3);
        gates[tid*4+0] = e0*iv; gates[tid*4+1] = e1*iv;
        gates[tid*4+2] = e2*iv; gates[tid*4+3] = e3*iv;
    }
    __syncthreads();
    int tk = tid >> 7;
    int hh = tid & 127;
    const float4* ltok4 = (const float4*)ltok;
    const float4* hdn4  = (const float4*)hdn;
    float outv[16];
    #pragma unroll
    for (int j = 0; j < 16; j++)
        outv[j] = ltok[(tk + 2*j)*132 + hh];      // residual init
    for (int e = 0; e < 4; e++) {
        float acc[16];
        float bv = b1[e*128 + hh];
        #pragma unroll
        for (int j = 0; j < 16; j++) acc[j] = bv;
        for (int c4 = 0; c4 < 32; c4++) {
            int c = c4*4;
            float wa = w1[(e*128 + c+0)*128 + hh];
            float wb = w1[(e*128 + c+1)*128 + hh];
            float wc = w1[(e*128 + c+2)*128 + hh];
            float wd = w1[(e*128 + c+3)*128 + hh];
            #pragma unroll
            for (int j = 0; j < 16; j++) {
                float4 tv = ltok4[(tk + 2*j)*33 + c4];   // LDS b128 broadcast
                acc[j] += tv.x*wa + tv.y*wb + tv.z*wc + tv.w*wd;
            }
        }
        #pragma unroll
        for (int j = 0; j < 16; j++) {
            float xv = acc[j];
            float th = tanhf(0.7978845608028654f*(xv + 0.044715f*xv*xv*xv));
            hdn[(tk + 2*j)*132 + hh] = 0.5f*xv*(1.f + th);   // gelu(tanh approx)
        }
        __syncthreads();
        float acc2[16];
        float b2v = b2[e*128 + hh];
        #pragma unroll
        for (int j = 0; j < 16; j++) acc2[j] = b2v;
        for (int h4 = 0; h4 < 32; h4++) {
            int hb = h4*4;
            float wa = w2[(e*128 + hb+0)*128 + hh];
            float wb = w2[(e*128 + hb+1)*128 + hh];
            float wc = w2[(e*128 + hb+2)*128 + hh];
            float wd = w2[(e*128 + hb+3)*128 + hh];
            #pragma unroll
            for (int j = 0; j < 16; j++) {
                float4 hv = hdn4[(tk + 2*j)*33 + h4];
                acc2[j] += hv.x*wa + hv.y*wb + hv.z*wc + hv.w*wd;
            }
        }
        #pragma unroll
        for (int j = 0; j < 16; j++)
            outv[j] += gates[(tk + 2*j)*4 + e] * acc2[j];
        __syncthreads();
    }
    #pragma unroll
    for (int j = 0; j < 16; j++)
        xo[(size_t)(tok0 + tk + 2*j)*128 + hh] = outv[j];
}

// ---------------- Stage 4: layout-A -> (2,B,T,D,H,W) ----------------
__global__ __launch_bounds__(256) void k_out(
    const float* __restrict__ xf, float* __restrict__ out)
{
    __shared__ float tile[64*129];
    int bt  = blockIdx.x;
    int hw0 = blockIdx.y * 64;
    int tid = threadIdx.x;
    for (int l = tid; l < 8192; l += 256)
        tile[(l >> 7)*129 + (l & 127)] = xf[(size_t)(bt*HW + hw0)*128 + l];
    __syncthreads();
    int wl = tid & 63;
    int q  = tid >> 6;
    for (int c = q; c < 128; c += 4) {
        int p = c >> 6, d = c & 63;
        out[((size_t)(p*32 + bt)*64 + d)*HW + hw0 + wl] = tile[wl*129 + c];
    }
}

extern "C" void kernel_launch(void* const* d_in, const int* in_sizes, int n_in,
                              void* d_out, int out_size, void* d_ws, size_t ws_size,
                              hipStream_t stream)
{
    const float* x_real = (const float*)d_in[0];
    const float* x_imag = (const float*)d_in[1];
    const float* dt     = (const float*)d_in[2];
    const float* nzr    = (const float*)d_in[3];
    const float* nzi    = (const float*)d_in[4];
    const float* ln_s_w = (const float*)d_in[5];
    const float* ln_s_b = (const float*)d_in[6];
    const float* conv_w = (const float*)d_in[7];
    const float* conv_b = (const float*)d_in[8];
    const float* ln_t_w = (const float*)d_in[9];
    const float* ln_t_b = (const float*)d_in[10];
    const float* lam_re = (const float*)d_in[11];
    const float* lam_im = (const float*)d_in[12];
    const float* sbr    = (const float*)d_in[13];
    const float* sbi    = (const float*)d_in[14];
    const float* enc_re = (const float*)d_in[15];
    const float* enc_im = (const float*)d_in[16];
    const float* dec_re = (const float*)d_in[17];
    const float* dec_im = (const float*)d_in[18];
    const float* rw     = (const float*)d_in[19];
    const float* rb     = (const float*)d_in[20];
    const float* w1     = (const float*)d_in[21];
    const float* b1     = (const float*)d_in[22];
    const float* w2     = (const float*)d_in[23];
    const float* b2     = (const float*)d_in[24];

    // ws: two 64 MiB fp32 buffers in channel-contiguous layout-A (BT,HW,128)
    float* buf0 = (float*)d_ws;
    float* buf1 = buf0 + 16777216;
    float* outp = (float*)d_out;

    k_ln_s   <<<dim3(32,64), 256, 0, stream>>>(x_real, x_imag, ln_s_w, ln_s_b, buf0);
    k_conv   <<<dim3(32,64), 128, 0, stream>>>(buf0, conv_w, conv_b, x_real, x_imag, buf1);
    k_temporal<<<8192,        64, 0, stream>>>(buf1, buf0, ln_t_w, ln_t_b, dt,
                                               lam_re, lam_im, sbr, sbi,
                                               enc_re, enc_im, dec_re, dec_im, nzr, nzi);
    k_moe    <<<4096,        256, 0, stream>>>(buf0, buf1, rw, rb, w1, b1, w2, b2);
    k_out    <<<dim3(32,64), 256, 0, stream>>>(buf1, outp);
}

// Round 2
// 676.716 us; speedup vs baseline: 3.1218x; 3.1218x over previous
//
#include <hip/hip_runtime.h>
#include <hip/hip_bf16.h>
#include <math.h>

#define HW 4096

typedef __attribute__((ext_vector_type(8))) short bf16x8;
typedef __attribute__((ext_vector_type(4))) float f32x4;

#define MFMA_BF16(a, b, c) __builtin_amdgcn_mfma_f32_16x16x32_bf16((a), (b), (c), 0, 0, 0)

static __device__ __forceinline__ float bf2f(short s) {
    unsigned int u = ((unsigned int)(unsigned short)s) << 16;
    return __uint_as_float(u);
}

// ---------------- Prep: fp32 [nmat][128][128] -> bf16 [nmat][128][128] transposed ----------------
__global__ __launch_bounds__(256) void k_prep_t(
    const float* __restrict__ src, __hip_bfloat16* __restrict__ dst)
{
    __shared__ float t[32*33];
    int m  = blockIdx.x;
    int tr = blockIdx.y >> 2, tc = blockIdx.y & 3;
    int tid = threadIdx.x;
    for (int l = tid; l < 1024; l += 256) {
        int r = l >> 5, c = l & 31;
        t[r*33 + c] = src[m*16384 + (tr*32 + r)*128 + (tc*32 + c)];
    }
    __syncthreads();
    for (int l = tid; l < 1024; l += 256) {
        int c = l >> 5, r = l & 31;
        dst[m*16384 + (tc*32 + c)*128 + (tr*32 + r)] = __float2bfloat16(t[r*33 + c]);
    }
}

// ---------------- Stage 1a: spatial complex LayerNorm -> bf16 layout-A ----------------
__global__ __launch_bounds__(256) void k_ln_s(
    const float* __restrict__ xr, const float* __restrict__ xi,
    const float* __restrict__ lw, const float* __restrict__ lb,
    __hip_bfloat16* __restrict__ out)
{
    __shared__ float tile[64*129];
    __shared__ float ps[64*4];
    __shared__ float ps2[64*4];
    __shared__ float mu_s[64];
    __shared__ float rs_s[64];
    int bt  = blockIdx.x;
    int hw0 = blockIdx.y * 64;
    int tid = threadIdx.x;
    int wl = tid & 63;
    int q  = tid >> 6;
    float s = 0.f, s2 = 0.f;
    for (int c = q; c < 128; c += 4) {
        const float* src = (c < 64) ? xr : xi;
        int d = c & 63;
        float v = src[(bt*64 + d)*HW + hw0 + wl];
        tile[wl*129 + c] = v;
        s += v; s2 += v*v;
    }
    ps[wl*4 + q] = s;
    ps2[wl*4 + q] = s2;
    __syncthreads();
    if (tid < 64) {
        float ss = ps[tid*4+0]+ps[tid*4+1]+ps[tid*4+2]+ps[tid*4+3];
        float qq = ps2[tid*4+0]+ps2[tid*4+1]+ps2[tid*4+2]+ps2[tid*4+3];
        float mu = ss * 0.0078125f;
        float var = qq * 0.0078125f - mu*mu;
        mu_s[tid] = mu;
        rs_s[tid] = rsqrtf(var + 1e-5f);
    }
    __syncthreads();
    int c = tid & 127;
    int r = tid >> 7;
    float wc = lw[c], bc = lb[c];
    for (int wi = r; wi < 64; wi += 2) {
        float v = tile[wi*129 + c];
        out[(size_t)(bt*HW + hw0 + wi)*128 + c] =
            __float2bfloat16((v - mu_s[wi]) * rs_s[wi] * wc + bc);
    }
}

// ---------------- Stage 1b: 3x3 conv via MFMA implicit GEMM + bias + residual ----------------
// grid (bt=32, h=64), 256 threads = 4 waves. Each wave: 64 tokens x 32 oc.
__global__ __launch_bounds__(256) void k_conv_mfma(
    const __hip_bfloat16* __restrict__ xc,   // (BT,HW,128) bf16
    const __hip_bfloat16* __restrict__ wB,   // (9,128 oc,128 ic) bf16
    const float* __restrict__ cb,
    const float* __restrict__ xr, const float* __restrict__ xi,
    float* __restrict__ x1)
{
    // 3 input rows x 66 px (w=-1..64) x 128 ch, pitch 136 bf16 (272 B -> 2-way banks, free)
    __shared__ __align__(16) short inrow[3*66*136];   // 53856 B
    int bt = blockIdx.x, h = blockIdx.y;
    int tid = threadIdx.x;
    // zero the left/right pad pixels (3 rows x 2 px x 16 chunks)
    if (tid < 96) {
        int r = tid / 32, t2 = tid & 31;
        int px = (t2 & 1) ? 65 : 0;
        int j = t2 >> 1;
        *(float4*)&inrow[(r*66 + px)*136 + j*8] = make_float4(0.f,0.f,0.f,0.f);
    }
    // interior: 3 rows x 64 px x 16 chunks of 8 bf16
    for (int c = tid; c < 3072; c += 256) {
        int r   = c >> 10;
        int rem = c & 1023;
        int px  = rem >> 4;
        int j   = rem & 15;
        int gh  = h + r - 1;
        float4 v = make_float4(0.f,0.f,0.f,0.f);
        if ((unsigned)gh < 64u)
            v = *(const float4*)&xc[(size_t)((bt*HW + gh*64 + px)*128) + j*8];
        *(float4*)&inrow[(r*66 + px + 1)*136 + j*8] = v;
    }
    __syncthreads();

    int wv = tid >> 6, l = tid & 63, lm = l & 15, q = l >> 4;
    int n0 = wv * 32;
    f32x4 acc[4][2];
    #pragma unroll
    for (int mi = 0; mi < 4; mi++)
        #pragma unroll
        for (int ni = 0; ni < 2; ni++)
            acc[mi][ni] = (f32x4){0.f,0.f,0.f,0.f};

    for (int p = 0; p < 9; p++) {
        int kh = p / 3, kw = p - kh*3;
        const __hip_bfloat16* wp = wB + p*16384;
        int abase = (kh*66 + kw)*136;
        #pragma unroll
        for (int ks = 0; ks < 4; ks++) {
            int ko = ks*32 + q*8;
            bf16x8 b0 = *(const bf16x8*)(wp + (n0 + lm)*128 + ko);       // L2 stream
            bf16x8 b1 = *(const bf16x8*)(wp + (n0 + 16 + lm)*128 + ko);
            #pragma unroll
            for (int mi = 0; mi < 4; mi++) {
                bf16x8 a = *(const bf16x8*)&inrow[abase + (mi*16 + lm)*136 + ko];
                acc[mi][0] = MFMA_BF16(a, b0, acc[mi][0]);
                acc[mi][1] = MFMA_BF16(a, b1, acc[mi][1]);
            }
        }
    }
    // epilogue: + bias + residual(original x, native layout), store fp32 layout-A
    #pragma unroll
    for (int ni = 0; ni < 2; ni++) {
        int oc = n0 + ni*16 + lm;
        float bias = cb[oc];
        const float* rsp = (oc < 64) ? xr : xi;
        const float* rbase = &rsp[(bt*64 + (oc & 63))*HW + h*64];
        #pragma unroll
        for (int mi = 0; mi < 4; mi++) {
            #pragma unroll
            for (int r = 0; r < 4; r++) {
                int w = mi*16 + q*4 + r;
                x1[(size_t)(bt*HW + h*64 + w)*128 + oc] = acc[mi][ni][r] + bias + rbase[w];
            }
        }
    }
}

// ---------------- Stage 2: temporal LN + encode + scan + decode + residual (in place) ----------------
__global__ __launch_bounds__(64) void k_temporal(
    float* xio,                              // fp32 layout-A, in/out
    __hip_bfloat16* __restrict__ x2b,        // bf16 copy of output tokens
    const float* __restrict__ lw, const float* __restrict__ lb,
    const float* __restrict__ dt,
    const float* __restrict__ lamr, const float* __restrict__ lami,
    const float* __restrict__ sbr, const float* __restrict__ sbi,
    const float* __restrict__ encr, const float* __restrict__ enci,
    const float* __restrict__ decr, const float* __restrict__ deci,
    const float* __restrict__ nzr, const float* __restrict__ nzi)
{
    __shared__ float zA[2048];
    __shared__ float zB[2048];
    int n = blockIdx.x;
    int b = n >> 12;
    int hw = n & 4095;
    int e = threadIdx.x;
    float lwr = lw[e], lwi = lw[e+64], lbr = lb[e], lbi = lb[e+64];
    for (int t = 0; t < 16; t++) {
        const float* src = &xio[(size_t)((b*16 + t)*HW + hw)*128];
        float v0 = src[e];
        float v1 = src[e+64];
        zA[t*128 + e] = v0;
        zA[t*128 + 64 + e] = v1;
        float s = v0 + v1;
        float s2 = v0*v0 + v1*v1;
        #pragma unroll
        for (int off = 32; off > 0; off >>= 1) {
            s  += __shfl_down(s, off, 64);
            s2 += __shfl_down(s2, off, 64);
        }
        float mu  = __shfl(s, 0, 64) * 0.0078125f;
        float var = __shfl(s2, 0, 64) * 0.0078125f - mu*mu;
        float rsq = rsqrtf(var + 1e-5f);
        zB[t*128 + e]      = (v0 - mu)*rsq*lwr + lbr;
        zB[t*128 + 64 + e] = (v1 - mu)*rsq*lwi + lbi;
    }
    __syncthreads();
    float sr[16], si[16];
    #pragma unroll
    for (int t = 0; t < 16; t++) { sr[t] = 0.f; si[t] = 0.f; }
    const float4* zB4 = (const float4*)zB;
    for (int d4 = 0; d4 < 16; d4++) {
        int d = d4*4;
        float er0 = encr[(d+0)*64 + e], ei0 = enci[(d+0)*64 + e];
        float er1 = encr[(d+1)*64 + e], ei1 = enci[(d+1)*64 + e];
        float er2 = encr[(d+2)*64 + e], ei2 = enci[(d+2)*64 + e];
        float er3 = encr[(d+3)*64 + e], ei3 = enci[(d+3)*64 + e];
        #pragma unroll
        for (int t = 0; t < 16; t++) {
            float4 xr4 = zB4[t*32 + d4];
            float4 xi4 = zB4[t*32 + 16 + d4];
            sr[t] += xr4.x*er0 - xi4.x*ei0 + xr4.y*er1 - xi4.y*ei1
                   + xr4.z*er2 - xi4.z*ei2 + xr4.w*er3 - xi4.w*ei3;
            si[t] += xr4.x*ei0 + xi4.x*er0 + xr4.y*ei1 + xi4.y*er1
                   + xr4.z*ei2 + xi4.z*er2 + xr4.w*ei3 + xi4.w*er3;
        }
    }
    float lr = lamr[e];
    float sp = (lr > 20.f) ? lr : log1pf(expf(lr));
    float lre = -sp;
    float lim = lami[e];
    float inv = 1.f / (lre*lre + lim*lim);
    float br = sbr[e], bi = sbi[e];
    float hrp = 0.f, hip = 0.f;
    float hsr[16], hsi[16];
    #pragma unroll
    for (int t = 0; t < 16; t++) {
        float dtv = dt[b*16 + t];
        float ex = expf(lre*dtv);
        float sn, cs;
        sincosf(lim*dtv, &sn, &cs);
        float ar = ex*cs, ai = ex*sn;
        float numr = ar - 1.f, numi = ai;
        float fr = (numr*lre + numi*lim)*inv;
        float fi = (numi*lre - numr*lim)*inv;
        float tr = sr[t] + br, ti = si[t] + bi;
        float ur = tr*fr - ti*fi;
        float ui = tr*fi + ti*fr;
        float nsc = 0.01f * sqrtf(dtv);
        ur += nsc * nzr[(size_t)(n*16 + t)*64 + e];
        ui += nsc * nzi[(size_t)(n*16 + t)*64 + e];
        float nh_r = ar*hrp - ai*hip + ur;
        float nh_i = ar*hip + ai*hrp + ui;
        hrp = nh_r; hip = nh_i;
        hsr[t] = hrp; hsi[t] = hip;
    }
    __syncthreads();
    #pragma unroll
    for (int t = 0; t < 16; t++) {
        zB[t*128 + e]      = hsr[t];
        zB[t*128 + 64 + e] = hsi[t];
    }
    __syncthreads();
    float drf[16];
    #pragma unroll
    for (int t = 0; t < 16; t++) drf[t] = 0.f;
    for (int e4 = 0; e4 < 16; e4++) {
        int ee = e4*4;
        float d0 = decr[(ee+0)*64 + e], i0 = deci[(ee+0)*64 + e];
        float d1 = decr[(ee+1)*64 + e], i1 = deci[(ee+1)*64 + e];
        float d2 = decr[(ee+2)*64 + e], i2 = deci[(ee+2)*64 + e];
        float d3 = decr[(ee+3)*64 + e], i3 = deci[(ee+3)*64 + e];
        #pragma unroll
        for (int t = 0; t < 16; t++) {
            float4 hr4 = zB4[t*32 + e4];
            float4 hi4 = zB4[t*32 + 16 + e4];
            drf[t] += hr4.x*d0 - hi4.x*i0 + hr4.y*d1 - hi4.y*i1
                    + hr4.z*d2 - hi4.z*i2 + hr4.w*d3 - hi4.w*i3;
        }
    }
    #pragma unroll
    for (int t = 0; t < 16; t++) {
        size_t idx = (size_t)((b*16 + t)*HW + hw)*128;
        float vr = drf[t] + zA[t*128 + e];
        float vi = zA[t*128 + 64 + e];
        xio[idx + e] = vr;
        xio[idx + e + 64] = vi;
        x2b[idx + e] = __float2bfloat16(vr);
        x2b[idx + e + 64] = __float2bfloat16(vi);
    }
}

// ---------------- Stage 3: MoE FFN via MFMA (in place on xio) ----------------
// 64 tokens / block, 256 threads = 4 waves; wave: 64 tokens x 32 units.
__global__ __launch_bounds__(256) void k_moe_mfma(
    float* xio,
    const __hip_bfloat16* __restrict__ x2b,
    const float* __restrict__ rw, const float* __restrict__ rb,
    const __hip_bfloat16* __restrict__ w1b, const float* __restrict__ b1,
    const __hip_bfloat16* __restrict__ w2b, const float* __restrict__ b2)
{
    __shared__ __align__(16) short tokA[64*136];
    __shared__ __align__(16) short hidA[64*136];
    __shared__ float gates[256];
    int tok0 = blockIdx.x * 64;
    int tid = threadIdx.x;
    for (int c = tid; c < 1024; c += 256) {
        int t = c >> 4, j = c & 15;
        *(float4*)&tokA[t*136 + j*8] = *(const float4*)&x2b[(size_t)(tok0 + t)*128 + j*8];
    }
    __syncthreads();
    {   // router logits: tid = token*4 + e
        int t = tid >> 2, e = tid & 3;
        float acc = rb[e];
        for (int c = 0; c < 128; c += 4) {
            acc += bf2f(tokA[t*136 + c+0]) * rw[(c+0)*4 + e]
                 + bf2f(tokA[t*136 + c+1]) * rw[(c+1)*4 + e]
                 + bf2f(tokA[t*136 + c+2]) * rw[(c+2)*4 + e]
                 + bf2f(tokA[t*136 + c+3]) * rw[(c+3)*4 + e];
        }
        gates[tid] = acc;
    }
    __syncthreads();
    if (tid < 64) {
        float g0 = gates[tid*4+0], g1 = gates[tid*4+1];
        float g2 = gates[tid*4+2], g3 = gates[tid*4+3];
        float m = fmaxf(fmaxf(g0,g1), fmaxf(g2,g3));
        float e0 = expf(g0-m), e1 = expf(g1-m), e2 = expf(g2-m), e3 = expf(g3-m);
        float iv = 1.f/(e0+e1+e2+e3);
        gates[tid*4+0] = e0*iv; gates[tid*4+1] = e1*iv;
        gates[tid*4+2] = e2*iv; gates[tid*4+3] = e3*iv;
    }
    __syncthreads();

    int wv = tid >> 6, l = tid & 63, lm = l & 15, q = l >> 4;
    int n0 = wv * 32;
    f32x4 outa[4][2];
    #pragma unroll
    for (int mi = 0; mi < 4; mi++)
        #pragma unroll
        for (int ni = 0; ni < 2; ni++)
            outa[mi][ni] = (f32x4){0.f,0.f,0.f,0.f};

    for (int e = 0; e < 4; e++) {
        // GEMM1: hidden = tok @ w1[e]  (B-frags streamed from L2)
        f32x4 acc1[4][2];
        #pragma unroll
        for (int mi = 0; mi < 4; mi++)
            #pragma unroll
            for (int ni = 0; ni < 2; ni++)
                acc1[mi][ni] = (f32x4){0.f,0.f,0.f,0.f};
        const __hip_bfloat16* wp1 = w1b + e*16384;
        #pragma unroll
        for (int ks = 0; ks < 4; ks++) {
            int ko = ks*32 + q*8;
            bf16x8 b0 = *(const bf16x8*)(wp1 + (n0 + lm)*128 + ko);
            bf16x8 b1v = *(const bf16x8*)(wp1 + (n0 + 16 + lm)*128 + ko);
            #pragma unroll
            for (int mi = 0; mi < 4; mi++) {
                bf16x8 a = *(const bf16x8*)&tokA[(mi*16 + lm)*136 + ko];
                acc1[mi][0] = MFMA_BF16(a, b0, acc1[mi][0]);
                acc1[mi][1] = MFMA_BF16(a, b1v, acc1[mi][1]);
            }
        }
        __syncthreads();   // previous expert's GEMM2 done reading hidA
        #pragma unroll
        for (int ni = 0; ni < 2; ni++) {
            int hcol = n0 + ni*16 + lm;
            float bb = b1[e*128 + hcol];
            #pragma unroll
            for (int mi = 0; mi < 4; mi++) {
                #pragma unroll
                for (int r = 0; r < 4; r++) {
                    float xv = acc1[mi][ni][r] + bb;
                    float targ = 0.7978845608028654f*(xv + 0.044715f*xv*xv*xv);
                    float hv = 0.5f*xv*(1.f + tanhf(targ));
                    int m = mi*16 + q*4 + r;
                    *(__hip_bfloat16*)&hidA[m*136 + hcol] = __float2bfloat16(hv);
                }
            }
        }
        __syncthreads();
        // GEMM2: yo = hidden @ w2[e]; out += gate_e * (yo + b2[e])
        f32x4 acc2[4][2];
        #pragma unroll
        for (int mi = 0; mi < 4; mi++)
            #pragma unroll
            for (int ni = 0; ni < 2; ni++)
                acc2[mi][ni] = (f32x4){0.f,0.f,0.f,0.f};
        const __hip_bfloat16* wp2 = w2b + e*16384;
        #pragma unroll
        for (int ks = 0; ks < 4; ks++) {
            int ko = ks*32 + q*8;
            bf16x8 b0 = *(const bf16x8*)(wp2 + (n0 + lm)*128 + ko);
            bf16x8 b1v = *(const bf16x8*)(wp2 + (n0 + 16 + lm)*128 + ko);
            #pragma unroll
            for (int mi = 0; mi < 4; mi++) {
                bf16x8 a = *(const bf16x8*)&hidA[(mi*16 + lm)*136 + ko];
                acc2[mi][0] = MFMA_BF16(a, b0, acc2[mi][0]);
                acc2[mi][1] = MFMA_BF16(a, b1v, acc2[mi][1]);
            }
        }
        #pragma unroll
        for (int ni = 0; ni < 2; ni++) {
            int ocol = n0 + ni*16 + lm;
            float bb = b2[e*128 + ocol];
            #pragma unroll
            for (int mi = 0; mi < 4; mi++) {
                #pragma unroll
                for (int r = 0; r < 4; r++) {
                    int m = mi*16 + q*4 + r;
                    float g = gates[m*4 + e];
                    outa[mi][ni][r] += g * (acc2[mi][ni][r] + bb);
                }
            }
        }
    }
    // epilogue: final = x2(fp32) + delta, in place
    #pragma unroll
    for (int ni = 0; ni < 2; ni++) {
        int col = n0 + ni*16 + lm;
        #pragma unroll
        for (int mi = 0; mi < 4; mi++) {
            #pragma unroll
            for (int r = 0; r < 4; r++) {
                int m = mi*16 + q*4 + r;
                size_t idx = (size_t)(tok0 + m)*128 + col;
                xio[idx] = xio[idx] + outa[mi][ni][r];
            }
        }
    }
}

// ---------------- Stage 4: layout-A -> (2,B,T,D,H,W) ----------------
__global__ __launch_bounds__(256) void k_out(
    const float* __restrict__ xf, float* __restrict__ out)
{
    __shared__ float tile[64*129];
    int bt  = blockIdx.x;
    int hw0 = blockIdx.y * 64;
    int tid = threadIdx.x;
    for (int l = tid; l < 8192; l += 256)
        tile[(l >> 7)*129 + (l & 127)] = xf[(size_t)(bt*HW + hw0)*128 + l];
    __syncthreads();
    int wl = tid & 63;
    int q  = tid >> 6;
    for (int c = q; c < 128; c += 4) {
        int p = c >> 6, d = c & 63;
        out[((size_t)(p*32 + bt)*64 + d)*HW + hw0 + wl] = tile[wl*129 + c];
    }
}

extern "C" void kernel_launch(void* const* d_in, const int* in_sizes, int n_in,
                              void* d_out, int out_size, void* d_ws, size_t ws_size,
                              hipStream_t stream)
{
    const float* x_real = (const float*)d_in[0];
    const float* x_imag = (const float*)d_in[1];
    const float* dt     = (const float*)d_in[2];
    const float* nzr    = (const float*)d_in[3];
    const float* nzi    = (const float*)d_in[4];
    const float* ln_s_w = (const float*)d_in[5];
    const float* ln_s_b = (const float*)d_in[6];
    const float* conv_w = (const float*)d_in[7];
    const float* conv_b = (const float*)d_in[8];
    const float* ln_t_w = (const float*)d_in[9];
    const float* ln_t_b = (const float*)d_in[10];
    const float* lam_re = (const float*)d_in[11];
    const float* lam_im = (const float*)d_in[12];
    const float* sbr    = (const float*)d_in[13];
    const float* sbi    = (const float*)d_in[14];
    const float* enc_re = (const float*)d_in[15];
    const float* enc_im = (const float*)d_in[16];
    const float* dec_re = (const float*)d_in[17];
    const float* dec_im = (const float*)d_in[18];
    const float* rw     = (const float*)d_in[19];
    const float* rb     = (const float*)d_in[20];
    const float* w1     = (const float*)d_in[21];
    const float* b1     = (const float*)d_in[22];
    const float* w2     = (const float*)d_in[23];
    const float* b2     = (const float*)d_in[24];

    char* ws = (char*)d_ws;
    float* bufA = (float*)ws;                                              // 64 MiB fp32 layout-A
    __hip_bfloat16* bufB = (__hip_bfloat16*)(ws + (size_t)64*1024*1024);   // 32 MiB bf16 layout-A
    __hip_bfloat16* wBc  = (__hip_bfloat16*)(ws + (size_t)96*1024*1024);   // conv weights bf16 [9][oc][ic]
    __hip_bfloat16* w1b  = wBc + 9*16384;                                  // [4][h][c]
    __hip_bfloat16* w2b  = w1b + 4*16384;                                  // [4][o][h]
    float* outp = (float*)d_out;

    k_prep_t<<<dim3(9,16), 256, 0, stream>>>(conv_w, wBc);
    k_prep_t<<<dim3(4,16), 256, 0, stream>>>(w1, w1b);
    k_prep_t<<<dim3(4,16), 256, 0, stream>>>(w2, w2b);

    k_ln_s     <<<dim3(32,64), 256, 0, stream>>>(x_real, x_imag, ln_s_w, ln_s_b, bufB);
    k_conv_mfma<<<dim3(32,64), 256, 0, stream>>>(bufB, wBc, conv_b, x_real, x_imag, bufA);
    k_temporal <<<8192,         64, 0, stream>>>(bufA, bufB, ln_t_w, ln_t_b, dt,
                                                 lam_re, lam_im, sbr, sbi,
                                                 enc_re, enc_im, dec_re, dec_im, nzr, nzi);
    k_moe_mfma <<<2048,        256, 0, stream>>>(bufA, bufB, rw, rb, w1b, b1, w2b, b2);
    k_out      <<<dim3(32,64), 256, 0, stream>>>(bufA, outp);
}

// Round 4
// 529.792 us; speedup vs baseline: 3.9876x; 1.2773x over previous
//
#include <hip/hip_runtime.h>
#include <hip/hip_bf16.h>
#include <math.h>

#define HW 4096
#define TP 264   // temporal A-tile pitch in halves: 528 B row stride == 4 mod 32 banks (2-way, free)

typedef __attribute__((ext_vector_type(8))) short bf16x8;
typedef _Float16 f16x8 __attribute__((ext_vector_type(8)));
typedef __attribute__((ext_vector_type(4))) float f32x4;

#define MFMA_BF16(a, b, c) __builtin_amdgcn_mfma_f32_16x16x32_bf16((a), (b), (c), 0, 0, 0)
#define MFMA_F16(a, b, c)  __builtin_amdgcn_mfma_f32_16x16x32_f16((a), (b), (c), 0, 0, 0)

static __device__ __forceinline__ float bf2f(short s) {
    unsigned int u = ((unsigned int)(unsigned short)s) << 16;
    return __uint_as_float(u);
}

// ---------------- Prep: fp32 [nmat][128][128] -> bf16 [nmat][128][128] transposed ----------------
__global__ __launch_bounds__(256) void k_prep_t(
    const float* __restrict__ src, __hip_bfloat16* __restrict__ dst)
{
    __shared__ float t[32*33];
    int m  = blockIdx.x;
    int tr = blockIdx.y >> 2, tc = blockIdx.y & 3;
    int tid = threadIdx.x;
    for (int l = tid; l < 1024; l += 256) {
        int r = l >> 5, c = l & 31;
        t[r*33 + c] = src[m*16384 + (tr*32 + r)*128 + (tc*32 + c)];
    }
    __syncthreads();
    for (int l = tid; l < 1024; l += 256) {
        int c = l >> 5, r = l & 31;
        dst[m*16384 + (tc*32 + c)*128 + (tr*32 + r)] = __float2bfloat16(t[r*33 + c]);
    }
}

// ---------------- Prep: temporal tables ----------------
// Benc  f16 [128n][128k]: n<64 -> u_re col e: [Er[k][e] | -Ei[k-64][e]]
//                         n>=64 -> u_im col e: [Ei[k][e] |  Er[k-64][e]]
// BdecX f16 [64n][256k] : k and k+128 hold the SAME value (hi/lo split accumulation)
//                         base (k<128): [Dr[k][d] | -Di[k-64][d]]
// coefG float4[(b*16+t)*64+e] = (a_re, a_im, f_re, f_im);  nscG[b*16+t] = 0.01*sqrt(dt)
__global__ __launch_bounds__(256) void k_prep_enc(
    const float* __restrict__ encr, const float* __restrict__ enci,
    const float* __restrict__ decr, const float* __restrict__ deci,
    const float* __restrict__ dt,
    const float* __restrict__ lamr, const float* __restrict__ lami,
    _Float16* __restrict__ Benc, _Float16* __restrict__ BdecX,
    float4* __restrict__ coefG, float* __restrict__ nscG)
{
    int idx = blockIdx.x*256 + threadIdx.x;
    if (idx < 16384) {
        int n = idx >> 7, k = idx & 127;
        int e = n & 63, d = k & 63;
        float v;
        if (n < 64) v = (k < 64) ? encr[d*64 + e] : -enci[d*64 + e];
        else        v = (k < 64) ? enci[d*64 + e] :  encr[d*64 + e];
        Benc[idx] = (_Float16)v;
    }
    if (idx < 16384) {
        int n = idx >> 8, k = idx & 255;
        int kk = k & 127;
        int e = kk & 63;
        float v = (kk < 64) ? decr[e*64 + n] : -deci[e*64 + n];
        BdecX[idx] = (_Float16)v;
    }
    if (idx < 2048) {
        int bt = idx >> 6, e = idx & 63;
        float dtv = dt[bt];
        float lr = lamr[e];
        float sp = (lr > 20.f) ? lr : log1pf(expf(lr));
        float lre = -sp, lim = lami[e];
        float inv = 1.f / (lre*lre + lim*lim);
        float ex = expf(lre*dtv);
        float sn, cs; sincosf(lim*dtv, &sn, &cs);
        float ar = ex*cs, ai = ex*sn;
        float fr = ((ar - 1.f)*lre + ai*lim)*inv;
        float fi = (ai*lre - (ar - 1.f)*lim)*inv;
        coefG[idx] = make_float4(ar, ai, fr, fi);
    }
    if (idx < 32) nscG[idx] = 0.01f * sqrtf(dt[idx]);
}

// ---------------- Stage 1a: spatial complex LayerNorm -> bf16 layout-A ----------------
__global__ __launch_bounds__(256) void k_ln_s(
    const float* __restrict__ xr, const float* __restrict__ xi,
    const float* __restrict__ lw, const float* __restrict__ lb,
    __hip_bfloat16* __restrict__ out)
{
    __shared__ float tile[64*129];
    __shared__ float ps[64*4];
    __shared__ float ps2[64*4];
    __shared__ float mu_s[64];
    __shared__ float rs_s[64];
    int bt  = blockIdx.x;
    int hw0 = blockIdx.y * 64;
    int tid = threadIdx.x;
    int wl = tid & 63;
    int q  = tid >> 6;
    float s = 0.f, s2 = 0.f;
    for (int c = q; c < 128; c += 4) {
        const float* src = (c < 64) ? xr : xi;
        int d = c & 63;
        float v = src[(bt*64 + d)*HW + hw0 + wl];
        tile[wl*129 + c] = v;
        s += v; s2 += v*v;
    }
    ps[wl*4 + q] = s;
    ps2[wl*4 + q] = s2;
    __syncthreads();
    if (tid < 64) {
        float ss = ps[tid*4+0]+ps[tid*4+1]+ps[tid*4+2]+ps[tid*4+3];
        float qq = ps2[tid*4+0]+ps2[tid*4+1]+ps2[tid*4+2]+ps2[tid*4+3];
        float mu = ss * 0.0078125f;
        float var = qq * 0.0078125f - mu*mu;
        mu_s[tid] = mu;
        rs_s[tid] = rsqrtf(var + 1e-5f);
    }
    __syncthreads();
    int c = tid & 127;
    int r = tid >> 7;
    float wc = lw[c], bc = lb[c];
    for (int wi = r; wi < 64; wi += 2) {
        float v = tile[wi*129 + c];
        out[(size_t)(bt*HW + hw0 + wi)*128 + c] =
            __float2bfloat16((v - mu_s[wi]) * rs_s[wi] * wc + bc);
    }
}

// ---------------- Stage 1b: 3x3 conv via MFMA implicit GEMM + bias + residual ----------------
__global__ __launch_bounds__(256) void k_conv_mfma(
    const __hip_bfloat16* __restrict__ xc,
    const __hip_bfloat16* __restrict__ wB,
    const float* __restrict__ cb,
    const float* __restrict__ xr, const float* __restrict__ xi,
    float* __restrict__ x1)
{
    __shared__ __align__(16) short inrow[3*66*136];
    int bt = blockIdx.x, h = blockIdx.y;
    int tid = threadIdx.x;
    if (tid < 96) {
        int r = tid / 32, t2 = tid & 31;
        int px = (t2 & 1) ? 65 : 0;
        int j = t2 >> 1;
        *(float4*)&inrow[(r*66 + px)*136 + j*8] = make_float4(0.f,0.f,0.f,0.f);
    }
    for (int c = tid; c < 3072; c += 256) {
        int r   = c >> 10;
        int rem = c & 1023;
        int px  = rem >> 4;
        int j   = rem & 15;
        int gh  = h + r - 1;
        float4 v = make_float4(0.f,0.f,0.f,0.f);
        if ((unsigned)gh < 64u)
            v = *(const float4*)&xc[(size_t)((bt*HW + gh*64 + px)*128) + j*8];
        *(float4*)&inrow[(r*66 + px + 1)*136 + j*8] = v;
    }
    __syncthreads();

    int wv = tid >> 6, l = tid & 63, lm = l & 15, q = l >> 4;
    int n0 = wv * 32;
    f32x4 acc[4][2];
    #pragma unroll
    for (int mi = 0; mi < 4; mi++)
        #pragma unroll
        for (int ni = 0; ni < 2; ni++)
            acc[mi][ni] = (f32x4){0.f,0.f,0.f,0.f};

    for (int p = 0; p < 9; p++) {
        int kh = p / 3, kw = p - kh*3;
        const __hip_bfloat16* wp = wB + p*16384;
        int abase = (kh*66 + kw)*136;
        #pragma unroll
        for (int ks = 0; ks < 4; ks++) {
            int ko = ks*32 + q*8;
            bf16x8 b0 = *(const bf16x8*)(wp + (n0 + lm)*128 + ko);
            bf16x8 b1 = *(const bf16x8*)(wp + (n0 + 16 + lm)*128 + ko);
            #pragma unroll
            for (int mi = 0; mi < 4; mi++) {
                bf16x8 a = *(const bf16x8*)&inrow[abase + (mi*16 + lm)*136 + ko];
                acc[mi][0] = MFMA_BF16(a, b0, acc[mi][0]);
                acc[mi][1] = MFMA_BF16(a, b1, acc[mi][1]);
            }
        }
    }
    #pragma unroll
    for (int ni = 0; ni < 2; ni++) {
        int oc = n0 + ni*16 + lm;
        float bias = cb[oc];
        const float* rsp = (oc < 64) ? xr : xi;
        const float* rbase = &rsp[(bt*64 + (oc & 63))*HW + h*64];
        #pragma unroll
        for (int mi = 0; mi < 4; mi++) {
            #pragma unroll
            for (int r = 0; r < 4; r++) {
                int w = mi*16 + q*4 + r;
                x1[(size_t)(bt*HW + h*64 + w)*128 + oc] = acc[mi][ni][r] + bias + rbase[w];
            }
        }
    }
}

// ---------------- Stage 2: temporal via MFMA, f16 + hi/lo-split decode ----------------
// block = 128 thr / 2 waves, 4 pixels. A-tile 64 rows = (n_local,t), pitch 264:
// cols 0..127 = z then h_hi [re|im]; cols 128..255 = h_lo [re|im].
// GEMM1 (encode, K=128) -> in-fragment complex scan -> h hi/lo to tile -> GEMM2 (decode, K=256).
__global__ __launch_bounds__(128) void k_temporal_mfma(
    float* xio,
    const float* __restrict__ lw, const float* __restrict__ lb,
    const float* __restrict__ sbr, const float* __restrict__ sbi,
    const _Float16* __restrict__ Benc, const _Float16* __restrict__ BdecX,
    const float4* __restrict__ coefG, const float* __restrict__ nscG,
    const float* __restrict__ nzr, const float* __restrict__ nzi)
{
    __shared__ __align__(16) short At[64*TP];   // 33792 B
    int n0  = blockIdx.x * 4;
    int b   = n0 >> 12;
    int hw0 = n0 & 4095;
    int tid = threadIdx.x;

    // LN: 2 threads per row (row = n_local*16 + t), f16 into A-tile cols 0..127
    {
        int row = tid >> 1, half = tid & 1;
        int nl = row >> 4, t = row & 15;
        const float4* src = (const float4*)&xio[((size_t)((b*16 + t)*HW) + hw0 + nl)*128 + half*64];
        float4 v[16];
        float s = 0.f, s2 = 0.f;
        #pragma unroll
        for (int j = 0; j < 16; j++) {
            v[j] = src[j];
            s  += v[j].x + v[j].y + v[j].z + v[j].w;
            s2 += v[j].x*v[j].x + v[j].y*v[j].y + v[j].z*v[j].z + v[j].w*v[j].w;
        }
        s  += __shfl_xor(s, 1, 64);
        s2 += __shfl_xor(s2, 1, 64);
        float mu  = s * 0.0078125f;
        float var = s2 * 0.0078125f - mu*mu;
        float rsq = rsqrtf(var + 1e-5f);
        const float4* lw4 = (const float4*)(lw + half*64);
        const float4* lb4 = (const float4*)(lb + half*64);
        short* dstrow = &At[row*TP + half*64];
        #pragma unroll
        for (int j = 0; j < 16; j++) {
            float4 wv4 = lw4[j], bv = lb4[j];
            union { _Float16 h[4]; float2 f; } u;
            u.h[0] = (_Float16)((v[j].x - mu)*rsq*wv4.x + bv.x);
            u.h[1] = (_Float16)((v[j].y - mu)*rsq*wv4.y + bv.y);
            u.h[2] = (_Float16)((v[j].z - mu)*rsq*wv4.z + bv.z);
            u.h[3] = (_Float16)((v[j].w - mu)*rsq*wv4.w + bv.w);
            *(float2*)(dstrow + j*4) = u.f;
        }
    }
    __syncthreads();   // coef/LN cross-wave publish; tile rows are wave-private below

    int wv = tid >> 6, l = tid & 63, lm = l & 15, q = l >> 4;

    // GEMM1: u_pre = z @ Benc  (ni<4 = re cols, ni+4 = im cols)
    f32x4 acc[2][8];
    #pragma unroll
    for (int mi = 0; mi < 2; mi++)
        #pragma unroll
        for (int ni = 0; ni < 8; ni++)
            acc[mi][ni] = (f32x4){0.f,0.f,0.f,0.f};
    #pragma unroll
    for (int ks = 0; ks < 4; ks++) {
        int ko = ks*32 + q*8;
        f16x8 a0 = *(const f16x8*)&At[((2*wv+0)*16 + lm)*TP + ko];
        f16x8 a1 = *(const f16x8*)&At[((2*wv+1)*16 + lm)*TP + ko];
        #pragma unroll
        for (int ni = 0; ni < 8; ni++) {
            f16x8 bb = *(const f16x8*)(Benc + (ni*16 + lm)*128 + ko);
            acc[0][ni] = MFMA_F16(a0, bb, acc[0][ni]);
            acc[1][ni] = MFMA_F16(a1, bb, acc[1][ni]);
        }
    }

    // in-fragment complex scan (coef from global table); write h hi/lo into wave rows
    int btbase = b*16;
    #pragma unroll
    for (int ni = 0; ni < 4; ni++) {
        int e = ni*16 + lm;
        float br = sbr[e], bi = sbi[e];
        float4 cf[4]; float ns[4];
        #pragma unroll
        for (int r = 0; r < 4; r++) {
            int t = q*4 + r;
            cf[r] = coefG[(btbase + t)*64 + e];
            ns[r] = nscG[btbase + t];
        }
        #pragma unroll
        for (int mi = 0; mi < 2; mi++) {
            int nl = 2*wv + mi;
            int ng = n0 + nl;
            float nrv[4], niv[4];
            #pragma unroll
            for (int r = 0; r < 4; r++) {
                int off = (ng*16 + q*4 + r)*64 + e;
                nrv[r] = nzr[off];
                niv[r] = nzi[off];
            }
            float hr = 0.f, hi = 0.f, Apr = 1.f, Api = 0.f;
            float hrs[4], his[4], Aprs[4], Apis[4];
            #pragma unroll
            for (int r = 0; r < 4; r++) {
                float Sr = acc[mi][ni][r] + br;
                float Si = acc[mi][ni+4][r] + bi;
                float ur = Sr*cf[r].z - Si*cf[r].w + ns[r]*nrv[r];
                float ui = Sr*cf[r].w + Si*cf[r].z + ns[r]*niv[r];
                if (r == 0) { hr = ur; hi = ui; Apr = cf[0].x; Api = cf[0].y; }
                else {
                    float tr = cf[r].x*hr - cf[r].y*hi + ur;
                    float ti = cf[r].x*hi + cf[r].y*hr + ui;
                    hr = tr; hi = ti;
                    tr = cf[r].x*Apr - cf[r].y*Api;
                    ti = cf[r].x*Api + cf[r].y*Apr;
                    Apr = tr; Api = ti;
                }
                hrs[r] = hr; his[r] = hi; Aprs[r] = Apr; Apis[r] = Api;
            }
            // quad-prefix over segments (A,H): h_out = H + A*h_in
            float Ar = Apr, Ai = Api, Hr = hr, Hi = hi;
            #pragma unroll
            for (int off = 16; off <= 32; off <<= 1) {
                float pAr = __shfl_up(Ar, off, 64);
                float pAi = __shfl_up(Ai, off, 64);
                float pHr = __shfl_up(Hr, off, 64);
                float pHi = __shfl_up(Hi, off, 64);
                if (l >= off) {
                    Hr = Hr + Ar*pHr - Ai*pHi;
                    Hi = Hi + Ar*pHi + Ai*pHr;
                    float tAr = Ar*pAr - Ai*pAi;
                    float tAi = Ar*pAi + Ai*pAr;
                    Ar = tAr; Ai = tAi;
                }
            }
            float gr = __shfl_up(Hr, 16, 64);
            float gi = __shfl_up(Hi, 16, 64);
            if (q == 0) { gr = 0.f; gi = 0.f; }
            #pragma unroll
            for (int r = 0; r < 4; r++) {
                float fhr = hrs[r] + Aprs[r]*gr - Apis[r]*gi;
                float fhi = his[r] + Aprs[r]*gi + Apis[r]*gr;
                int row = nl*16 + q*4 + r;
                _Float16 hrh = (_Float16)fhr;
                _Float16 hih = (_Float16)fhi;
                *(_Float16*)&At[row*TP + e]        = hrh;
                *(_Float16*)&At[row*TP + 64 + e]   = hih;
                *(_Float16*)&At[row*TP + 128 + e]  = (_Float16)(fhr - (float)hrh);
                *(_Float16*)&At[row*TP + 192 + e]  = (_Float16)(fhi - (float)hih);
            }
        }
    }

    // GEMM2: drift = (h_hi + h_lo) @ BdecX  (K=256, duplicated weights)
    f32x4 acc2[2][4];
    #pragma unroll
    for (int mi = 0; mi < 2; mi++)
        #pragma unroll
        for (int ni = 0; ni < 4; ni++)
            acc2[mi][ni] = (f32x4){0.f,0.f,0.f,0.f};
    #pragma unroll
    for (int ks = 0; ks < 8; ks++) {
        int ko = ks*32 + q*8;
        f16x8 a0 = *(const f16x8*)&At[((2*wv+0)*16 + lm)*TP + ko];
        f16x8 a1 = *(const f16x8*)&At[((2*wv+1)*16 + lm)*TP + ko];
        #pragma unroll
        for (int ni = 0; ni < 4; ni++) {
            f16x8 bb = *(const f16x8*)(BdecX + (ni*16 + lm)*256 + ko);
            acc2[0][ni] = MFMA_F16(a0, bb, acc2[0][ni]);
            acc2[1][ni] = MFMA_F16(a1, bb, acc2[1][ni]);
        }
    }

    // epilogue: xio.re += drift (in place, re-half only)
    #pragma unroll
    for (int mi = 0; mi < 2; mi++) {
        int nl = 2*wv + mi;
        #pragma unroll
        for (int ni = 0; ni < 4; ni++) {
            int d = ni*16 + lm;
            #pragma unroll
            for (int r = 0; r < 4; r++) {
                int t = q*4 + r;
                size_t idx = ((size_t)((b*16 + t)*HW) + hw0 + nl)*128 + d;
                xio[idx] = xio[idx] + acc2[mi][ni][r];
            }
        }
    }
}

// ---------------- Stage 3: MoE FFN via MFMA; writes FINAL output in native layout ----------------
__global__ __launch_bounds__(256) void k_moe_mfma(
    const float* __restrict__ xio,
    float* __restrict__ outp,
    const float* __restrict__ rw, const float* __restrict__ rb,
    const __hip_bfloat16* __restrict__ w1b, const float* __restrict__ b1,
    const __hip_bfloat16* __restrict__ w2b, const float* __restrict__ b2)
{
    __shared__ __align__(16) short smem[2*64*136];   // tokA | hidA; reused as fp32 tile 64x129
    __shared__ float gates[256];
    short* tokA = smem;
    short* hidA = smem + 64*136;
    float* tile = (float*)smem;
    int tok0 = blockIdx.x * 64;
    int tid = threadIdx.x;
    for (int lsd = tid; lsd < 2048; lsd += 256) {
        int t = lsd >> 5, j = lsd & 31;
        float4 v = *(const float4*)&xio[(size_t)(tok0 + t)*128 + j*4];
        union { __hip_bfloat16 h[4]; float2 f; } u;
        u.h[0] = __float2bfloat16(v.x);
        u.h[1] = __float2bfloat16(v.y);
        u.h[2] = __float2bfloat16(v.z);
        u.h[3] = __float2bfloat16(v.w);
        *(float2*)&tokA[t*136 + j*4] = u.f;
    }
    __syncthreads();
    {
        int t = tid >> 2, e = tid & 3;
        float acc = rb[e];
        for (int c = 0; c < 128; c += 4) {
            acc += bf2f(tokA[t*136 + c+0]) * rw[(c+0)*4 + e]
                 + bf2f(tokA[t*136 + c+1]) * rw[(c+1)*4 + e]
                 + bf2f(tokA[t*136 + c+2]) * rw[(c+2)*4 + e]
                 + bf2f(tokA[t*136 + c+3]) * rw[(c+3)*4 + e];
        }
        gates[tid] = acc;
    }
    __syncthreads();
    if (tid < 64) {
        float g0 = gates[tid*4+0], g1 = gates[tid*4+1];
        float g2 = gates[tid*4+2], g3 = gates[tid*4+3];
        float m = fmaxf(fmaxf(g0,g1), fmaxf(g2,g3));
        float e0 = expf(g0-m), e1 = expf(g1-m), e2 = expf(g2-m), e3 = expf(g3-m);
        float iv = 1.f/(e0+e1+e2+e3);
        gates[tid*4+0] = e0*iv; gates[tid*4+1] = e1*iv;
        gates[tid*4+2] = e2*iv; gates[tid*4+3] = e3*iv;
    }
    __syncthreads();

    int wv = tid >> 6, l = tid & 63, lm = l & 15, q = l >> 4;
    int n0 = wv * 32;
    f32x4 outa[4][2];
    #pragma unroll
    for (int mi = 0; mi < 4; mi++)
        #pragma unroll
        for (int ni = 0; ni < 2; ni++)
            outa[mi][ni] = (f32x4){0.f,0.f,0.f,0.f};

    for (int e = 0; e < 4; e++) {
        f32x4 acc1[4][2];
        #pragma unroll
        for (int mi = 0; mi < 4; mi++)
            #pragma unroll
            for (int ni = 0; ni < 2; ni++)
                acc1[mi][ni] = (f32x4){0.f,0.f,0.f,0.f};
        const __hip_bfloat16* wp1 = w1b + e*16384;
        #pragma unroll
        for (int ks = 0; ks < 4; ks++) {
            int ko = ks*32 + q*8;
            bf16x8 b0  = *(const bf16x8*)(wp1 + (n0 + lm)*128 + ko);
            bf16x8 b1v = *(const bf16x8*)(wp1 + (n0 + 16 + lm)*128 + ko);
            #pragma unroll
            for (int mi = 0; mi < 4; mi++) {
                bf16x8 a = *(const bf16x8*)&tokA[(mi*16 + lm)*136 + ko];
                acc1[mi][0] = MFMA_BF16(a, b0,  acc1[mi][0]);
                acc1[mi][1] = MFMA_BF16(a, b1v, acc1[mi][1]);
            }
        }
        __syncthreads();
        #pragma unroll
        for (int ni = 0; ni < 2; ni++) {
            int hcol = n0 + ni*16 + lm;
            float bb = b1[e*128 + hcol];
            #pragma unroll
            for (int mi = 0; mi < 4; mi++) {
                #pragma unroll
                for (int r = 0; r < 4; r++) {
                    float xv = acc1[mi][ni][r] + bb;
                    float targ = 0.7978845608028654f*(xv + 0.044715f*xv*xv*xv);
                    float hv = 0.5f*xv*(1.f + tanhf(targ));
                    int m = mi*16 + q*4 + r;
                    *(__hip_bfloat16*)&hidA[m*136 + hcol] = __float2bfloat16(hv);
                }
            }
        }
        __syncthreads();
        f32x4 acc2[4][2];
        #pragma unroll
        for (int mi = 0; mi < 4; mi++)
            #pragma unroll
            for (int ni = 0; ni < 2; ni++)
                acc2[mi][ni] = (f32x4){0.f,0.f,0.f,0.f};
        const __hip_bfloat16* wp2 = w2b + e*16384;
        #pragma unroll
        for (int ks = 0; ks < 4; ks++) {
            int ko = ks*32 + q*8;
            bf16x8 b0  = *(const bf16x8*)(wp2 + (n0 + lm)*128 + ko);
            bf16x8 b1v = *(const bf16x8*)(wp2 + (n0 + 16 + lm)*128 + ko);
            #pragma unroll
            for (int mi = 0; mi < 4; mi++) {
                bf16x8 a = *(const bf16x8*)&hidA[(mi*16 + lm)*136 + ko];
                acc2[mi][0] = MFMA_BF16(a, b0,  acc2[mi][0]);
                acc2[mi][1] = MFMA_BF16(a, b1v, acc2[mi][1]);
            }
        }
        #pragma unroll
        for (int ni = 0; ni < 2; ni++) {
            int ocol = n0 + ni*16 + lm;
            float bb = b2[e*128 + ocol];
            #pragma unroll
            for (int mi = 0; mi < 4; mi++) {
                #pragma unroll
                for (int r = 0; r < 4; r++) {
                    int m = mi*16 + q*4 + r;
                    float g = gates[m*4 + e];
                    outa[mi][ni][r] += g * (acc2[mi][ni][r] + bb);
                }
            }
        }
        __syncthreads();
    }
    // final = residual + delta -> LDS tile (pitch 129) -> native-layout store
    #pragma unroll
    for (int ni = 0; ni < 2; ni++) {
        int col = n0 + ni*16 + lm;
        #pragma unroll
        for (int mi = 0; mi < 4; mi++) {
            #pragma unroll
            for (int r = 0; r < 4; r++) {
                int m = mi*16 + q*4 + r;
                tile[m*129 + col] = xio[(size_t)(tok0 + m)*128 + col] + outa[mi][ni][r];
            }
        }
    }
    __syncthreads();
    int bt = tok0 >> 12;
    int hw0 = tok0 & 4095;
    for (int lid = tid; lid < 8192; lid += 256) {
        int c = lid >> 6, m = lid & 63;
        int p = c >> 6, d = c & 63;
        outp[((size_t)((p*32 + bt)*64 + d))*HW + hw0 + m] = tile[m*129 + c];
    }
}

extern "C" void kernel_launch(void* const* d_in, const int* in_sizes, int n_in,
                              void* d_out, int out_size, void* d_ws, size_t ws_size,
                              hipStream_t stream)
{
    const float* x_real = (const float*)d_in[0];
    const float* x_imag = (const float*)d_in[1];
    const float* dt     = (const float*)d_in[2];
    const float* nzr    = (const float*)d_in[3];
    const float* nzi    = (const float*)d_in[4];
    const float* ln_s_w = (const float*)d_in[5];
    const float* ln_s_b = (const float*)d_in[6];
    const float* conv_w = (const float*)d_in[7];
    const float* conv_b = (const float*)d_in[8];
    const float* ln_t_w = (const float*)d_in[9];
    const float* ln_t_b = (const float*)d_in[10];
    const float* lam_re = (const float*)d_in[11];
    const float* lam_im = (const float*)d_in[12];
    const float* sbr    = (const float*)d_in[13];
    const float* sbi    = (const float*)d_in[14];
    const float* enc_re = (const float*)d_in[15];
    const float* enc_im = (const float*)d_in[16];
    const float* dec_re = (const float*)d_in[17];
    const float* dec_im = (const float*)d_in[18];
    const float* rw     = (const float*)d_in[19];
    const float* rb     = (const float*)d_in[20];
    const float* w1     = (const float*)d_in[21];
    const float* b1     = (const float*)d_in[22];
    const float* w2     = (const float*)d_in[23];
    const float* b2     = (const float*)d_in[24];

    char* ws = (char*)d_ws;
    float* bufA = (float*)ws;                                              // 64 MiB fp32 layout-A
    __hip_bfloat16* bufB = (__hip_bfloat16*)(ws + (size_t)64*1024*1024);   // 32 MiB bf16 (ln_s -> conv)
    __hip_bfloat16* wBc  = (__hip_bfloat16*)(ws + (size_t)96*1024*1024);   // conv weights [9][oc][ic]
    __hip_bfloat16* w1b  = wBc + 9*16384;
    __hip_bfloat16* w2b  = w1b + 4*16384;
    _Float16* Benc  = (_Float16*)(w2b + 4*16384);                          // [128][128] f16
    _Float16* BdecX = Benc + 16384;                                        // [64][256] f16
    float4* coefG = (float4*)(BdecX + 16384);                              // [2048]
    float* nscG   = (float*)(coefG + 2048);                                // [32]
    float* outp = (float*)d_out;

    k_prep_t  <<<dim3(9,16), 256, 0, stream>>>(conv_w, wBc);
    k_prep_t  <<<dim3(4,16), 256, 0, stream>>>(w1, w1b);
    k_prep_t  <<<dim3(4,16), 256, 0, stream>>>(w2, w2b);
    k_prep_enc<<<64,         256, 0, stream>>>(enc_re, enc_im, dec_re, dec_im,
                                               dt, lam_re, lam_im,
                                               Benc, BdecX, coefG, nscG);

    k_ln_s         <<<dim3(32,64), 256, 0, stream>>>(x_real, x_imag, ln_s_w, ln_s_b, bufB);
    k_conv_mfma    <<<dim3(32,64), 256, 0, stream>>>(bufB, wBc, conv_b, x_real, x_imag, bufA);
    k_temporal_mfma<<<2048,        128, 0, stream>>>(bufA, ln_t_w, ln_t_b, sbr, sbi,
                                                     Benc, BdecX, coefG, nscG, nzr, nzi);
    k_moe_mfma     <<<2048,        256, 0, stream>>>(bufA, outp, rw, rb, w1b, b1, w2b, b2);
}